// Round 2
// baseline (4570.972 us; speedup 1.0000x reference)
//
#include <hip/hip_runtime.h>
#include <stdint.h>

// CondDecoder: B=256, T=128, V=64, L=128, H=512, E=32, NL=3, IN0=161 (pad 192)
#define BB 256
#define TT 128
#define HH 512
#define G3 1536

typedef __attribute__((ext_vector_type(8))) short bf16x8;
typedef __attribute__((ext_vector_type(4))) float f32x4;

__device__ __forceinline__ unsigned short f2bf(float f){
  unsigned int x = __builtin_bit_cast(unsigned int, f);
  x = x + 0x7fffu + ((x >> 16) & 1u);
  return (unsigned short)(x >> 16);
}
__device__ __forceinline__ float bf2f(unsigned short u){
  unsigned int x = ((unsigned int)u) << 16;
  return __builtin_bit_cast(float, x);
}
__device__ __forceinline__ void gl_lds16(const void* g, void* l){
  __builtin_amdgcn_global_load_lds((const __attribute__((address_space(1))) unsigned int*)g,
                                   (__attribute__((address_space(3))) unsigned int*)l, 16, 0, 0);
}

// ---- prep: convert five [1536][512] f32 weights to bf16 (Whh0..2, Wih1, Wih2)
__global__ __launch_bounds__(256) void kconv5(
    const float* __restrict__ a0, const float* __restrict__ a1, const float* __restrict__ a2,
    const float* __restrict__ a3, const float* __restrict__ a4,
    unsigned short* __restrict__ d0, unsigned short* __restrict__ d1, unsigned short* __restrict__ d2,
    unsigned short* __restrict__ d3, unsigned short* __restrict__ d4){
  int i = blockIdx.x*256 + threadIdx.x;   // grid 3072*256 = 786432 exactly
  d0[i] = f2bf(a0[i]); d1[i] = f2bf(a1[i]); d2[i] = f2bf(a2[i]);
  d3[i] = f2bf(a3[i]); d4[i] = f2bf(a4[i]);
}

// ---- prep: Wih0 pad 161->192 to bf16; fc_W transpose to [512][64] f32; zero counters
__global__ __launch_bounds__(256) void kmisc(const float* __restrict__ wih0,
    unsigned short* __restrict__ wih0p, const float* __restrict__ fcw,
    float* __restrict__ fcwt, int* __restrict__ cnt){
  int i = blockIdx.x*256 + threadIdx.x;  // grid 1152*256 = 294912
  if (i < 1536*192){
    int n = i / 192, k = i - n*192;
    wih0p[i] = (k < 161) ? f2bf(wih0[n*161 + k]) : (unsigned short)0;
  }
  if (i < 512*64){
    int k = i >> 6, v = i & 63;
    fcwt[i] = fcw[v*512 + k];
  }
  if (i < 2048) cnt[i] = 0;
}

// ---- prep: build x0 [32768][192] bf16 (latent | shifted-embed | enthalpy | zeros)
__global__ __launch_bounds__(192) void kx0(const float* __restrict__ latent,
    const float* __restrict__ enth, const int* __restrict__ inp,
    const float* __restrict__ emb, unsigned short* __restrict__ x0){
  int c = threadIdx.x;
  #pragma unroll
  for (int mr = 0; mr < 4; ++mr){
    int m = blockIdx.x*4 + mr;       // grid 8192 -> m < 32768
    int b = m >> 7, t = m & 127;
    float v;
    if (c < 128) v = latent[b*128 + c];
    else if (c < 160){
      int tok = (t == 0) ? 0 : inp[b*128 + t - 1];
      v = emb[tok*32 + (c - 128)];
    }
    else if (c == 160) v = enth[b];
    else v = 0.f;
    x0[(size_t)m*192 + c] = f2bf(v);
  }
}

// ---- bf16 MFMA GEMM: C[m][n] = A[m][K] @ Bt[n][K]^T + bias[n]; M=32768 fixed by grid
__global__ __launch_bounds__(256) void kgemm(const unsigned short* __restrict__ A,
    const unsigned short* __restrict__ Bt, const float* __restrict__ bias,
    void* __restrict__ C, int c_bf16, int N, int K){
  __shared__ __align__(16) unsigned short As[128*32];
  __shared__ __align__(16) unsigned short Bs[128*32];
  const int m0 = blockIdx.y*128, n0 = blockIdx.x*128;
  const int wv = threadIdx.x >> 6, lane = threadIdx.x & 63;
  const int woffM = (wv >> 1)*64, woffN = (wv & 1)*64;
  f32x4 acc[4][4] = {};
  for (int k0 = 0; k0 < K; k0 += 32){
    __syncthreads();
    #pragma unroll
    for (int i = 0; i < 4; ++i){
      int e = wv*4 + i;
      int ee = e & 7;
      int row = ee*16 + (lane >> 2);
      if (e < 8) gl_lds16(A  + (size_t)(m0+row)*K + k0 + (lane & 3)*8, (void*)&As[ee*512]);
      else       gl_lds16(Bt + (size_t)(n0+row)*K + k0 + (lane & 3)*8, (void*)&Bs[ee*512]);
    }
    __syncthreads();
    bf16x8 af[4], bf_[4];
    #pragma unroll
    for (int mt = 0; mt < 4; ++mt)
      af[mt] = *(const bf16x8*)&As[(woffM + mt*16 + (lane & 15))*32 + (lane >> 4)*8];
    #pragma unroll
    for (int nt = 0; nt < 4; ++nt)
      bf_[nt] = *(const bf16x8*)&Bs[(woffN + nt*16 + (lane & 15))*32 + (lane >> 4)*8];
    #pragma unroll
    for (int mt = 0; mt < 4; ++mt)
      #pragma unroll
      for (int nt = 0; nt < 4; ++nt)
        acc[mt][nt] = __builtin_amdgcn_mfma_f32_16x16x32_bf16(af[mt], bf_[nt], acc[mt][nt], 0, 0, 0);
  }
  const int col = lane & 15, lq = lane >> 4;
  #pragma unroll
  for (int nt = 0; nt < 4; ++nt){
    float bv = bias[n0 + woffN + nt*16 + col];
    #pragma unroll
    for (int mt = 0; mt < 4; ++mt)
      #pragma unroll
      for (int r = 0; r < 4; ++r){
        int grow = m0 + woffM + mt*16 + lq*4 + r;
        int gcol = n0 + woffN + nt*16 + col;
        float v = acc[mt][nt][r] + bv;
        size_t idx = (size_t)grow*N + gcol;
        if (c_bf16) ((unsigned short*)C)[idx] = f2bf(v);
        else        ((float*)C)[idx] = v;
      }
  }
}

// ---- persistent GRU layer kernel.
// 64 blocks x 768 threads (12 waves = 3 gates x 4 col-chunks).
// rg = blockIdx&7 (8 blocks/rowgroup land on ONE XCD under round-robin -> L2-local h).
// Whh frags resident in VGPRs (64/lane). h double-buffered in global, stored LINEAR
// coalesced; bank-swizzle applied on the gl_lds SOURCE address (rule #21), reads XOR'd.
// Sync: 32 per-slot release-STORES per rowgroup-step (no RMW contention), wave-ballot spin.
// xo stores after the release (sched_barrier pinned) and per-layer gated.
__global__ __launch_bounds__(768) void kgru(const unsigned short* __restrict__ Wb,
    const float* __restrict__ bhh, const void* __restrict__ gi, int gi_bf16,
    unsigned short* __restrict__ hb, unsigned short* __restrict__ xo_bf,
    float* __restrict__ xo_f, int* __restrict__ cnt, int store_bf, int store_f){
  const int rg = blockIdx.x & 7, cg = blockIdx.x >> 3;
  const int b0 = rg*32;
  const int wv = threadIdx.x >> 6, lane = threadIdx.x & 63;
  const int g = wv >> 2, cc = wv & 3;           // gate 0..2, col-chunk 0..3
  const int col = lane & 15, lq = lane >> 4;
  const int gcol = cg*64 + cc*16 + col;         // column within 512
  const int ccol = cc*16 + col;                 // column within block's 64
  __shared__ __align__(16) unsigned short hs[32*512];
  __shared__ float rz[2][32][68];               // padded stride 68: 2-way max (free)
  bf16x8 wf[16];
  {
    const unsigned short* wbase = Wb + ((size_t)(g*512 + gcol))*512 + lq*8;
    #pragma unroll
    for (int ks = 0; ks < 16; ++ks) wf[ks] = *(const bf16x8*)(wbase + ks*32);
  }
  const float bias = bhh[g*512 + gcol];
  float h_old[2][4];
  #pragma unroll
  for (int mt = 0; mt < 2; ++mt)
    #pragma unroll
    for (int r = 0; r < 4; ++r) h_old[mt][r] = 0.f;
  const float* gif = (const float*)gi;
  const unsigned short* gih = (const unsigned short*)gi;
  int* myc = cnt + rg*32;                       // 32 slots, one per (cg,cc) writer wave

  #pragma unroll 1
  for (int t = 0; t < TT; ++t){
    // gi loads issued early; latency hides under spin+stage+MFMA
    float gval[2][4];
    #pragma unroll
    for (int mt = 0; mt < 2; ++mt)
      #pragma unroll
      for (int r = 0; r < 4; ++r){
        size_t gidx = ((size_t)(b0 + mt*16 + lq*4 + r)*TT + t)*G3 + g*512 + gcol;
        gval[mt][r] = gi_bf16 ? bf2f(gih[gidx]) : gif[gidx];
      }
    f32x4 acc[2] = {};
    if (t > 0){
      if (wv == 0){                              // wave-parallel spin: lane watches one slot
        while (!__all(__hip_atomic_load(myc + (lane & 31), __ATOMIC_ACQUIRE,
                                        __HIP_MEMORY_SCOPE_AGENT) >= t))
          __builtin_amdgcn_s_sleep(1);
      }
      __syncthreads();
      const unsigned short* hr = hb + (t & 1)*131072 + (size_t)b0*512;
      for (int e = wv; e < 32; e += 12)          // linear LDS dest, swizzled global src
        gl_lds16(hr + e*512 + (size_t)((lane ^ (e & 7))*8), (void*)&hs[e*512]);
      __syncthreads();
      #pragma unroll
      for (int ks = 0; ks < 16; ++ks)
        #pragma unroll
        for (int mt = 0; mt < 2; ++mt){
          int row = mt*16 + col;
          bf16x8 a = *(const bf16x8*)&hs[row*512 + (((ks*4 + lq) ^ (row & 7)))*8];
          acc[mt] = __builtin_amdgcn_mfma_f32_16x16x32_bf16(a, wf[ks], acc[mt], 0, 0, 0);
        }
    }
    if (g < 2){
      #pragma unroll
      for (int mt = 0; mt < 2; ++mt)
        #pragma unroll
        for (int r = 0; r < 4; ++r){
          int row = mt*16 + lq*4 + r;
          float pre = gval[mt][r] + acc[mt][r] + bias;
          rz[g][row][ccol] = 1.f/(1.f + __expf(-pre));
        }
    }
    __syncthreads();
    if (g == 2){
      unsigned short* hw = hb + ((t + 1) & 1)*131072;
      unsigned short hv[2][4]; float hf[2][4];
      #pragma unroll
      for (int mt = 0; mt < 2; ++mt)
        #pragma unroll
        for (int r = 0; r < 4; ++r){
          int row = mt*16 + lq*4 + r;
          float rr = rz[0][row][ccol];
          float zz = rz[1][row][ccol];
          float nn = tanhf(gval[mt][r] + rr*(acc[mt][r] + bias));
          float hn = (1.f - zz)*nn + zz*h_old[mt][r];
          h_old[mt][r] = hn;
          hf[mt][r] = hn;
          hv[mt][r] = f2bf(hn);
          hw[(size_t)(b0 + row)*512 + gcol] = hv[mt][r];   // linear, coalesced
        }
      if (lane == 0)                                       // per-wave slot release-store
        __hip_atomic_store(myc + (cg*4 + cc), t + 1, __ATOMIC_RELEASE,
                           __HIP_MEMORY_SCOPE_AGENT);
      __builtin_amdgcn_sched_barrier(0);                   // keep xo stores AFTER release
      if (store_bf){
        #pragma unroll
        for (int mt = 0; mt < 2; ++mt)
          #pragma unroll
          for (int r = 0; r < 4; ++r){
            int row = mt*16 + lq*4 + r;
            xo_bf[((size_t)(b0 + row)*TT + t)*512 + gcol] = hv[mt][r];
          }
      }
      if (store_f){
        #pragma unroll
        for (int mt = 0; mt < 2; ++mt)
          #pragma unroll
          for (int r = 0; r < 4; ++r){
            int row = mt*16 + lq*4 + r;
            xo_f[((size_t)(b0 + row)*TT + t)*512 + gcol] = hf[mt][r];
          }
      }
    }
  }
}

// ---- final FC in f32 (precision): logits[m][64] = x[m][512] @ fcwt + fc_b
__global__ __launch_bounds__(256) void kfc(const float* __restrict__ x,
    const float* __restrict__ wt, const float* __restrict__ fcb, float* __restrict__ out){
  __shared__ __align__(16) float xs[16*512];
  const int m0 = blockIdx.x*16;   // grid 2048
  for (int c = threadIdx.x; c < 2048; c += 256){
    int row = c >> 7, o = c & 127;
    *(float4*)&xs[row*512 + o*4] = *(const float4*)(x + (size_t)(m0+row)*512 + o*4);
  }
  __syncthreads();
  const int colv = threadIdx.x & 63, rq = threadIdx.x >> 6;
  float a0 = 0.f, a1 = 0.f, a2 = 0.f, a3 = 0.f;
  const float* x0p = xs + (rq*4 + 0)*512;
  const float* x1p = xs + (rq*4 + 1)*512;
  const float* x2p = xs + (rq*4 + 2)*512;
  const float* x3p = xs + (rq*4 + 3)*512;
  #pragma unroll 8
  for (int k = 0; k < 512; ++k){
    float w = wt[k*64 + colv];
    a0 += w * x0p[k]; a1 += w * x1p[k]; a2 += w * x2p[k]; a3 += w * x3p[k];
  }
  float bv = fcb[colv];
  out[(size_t)(m0 + rq*4 + 0)*64 + colv] = a0 + bv;
  out[(size_t)(m0 + rq*4 + 1)*64 + colv] = a1 + bv;
  out[(size_t)(m0 + rq*4 + 2)*64 + colv] = a2 + bv;
  out[(size_t)(m0 + rq*4 + 3)*64 + colv] = a3 + bv;
}

extern "C" void kernel_launch(void* const* d_in, const int* in_sizes, int n_in,
                              void* d_out, int out_size, void* d_ws, size_t ws_size,
                              hipStream_t stream){
  const float* latent = (const float*)d_in[0];
  const float* enth   = (const float*)d_in[1];
  const int*   inp    = (const int*)d_in[2];
  const float* emb    = (const float*)d_in[3];
  const float* Wih0   = (const float*)d_in[4];
  const float* Whh0   = (const float*)d_in[5];
  const float* bih0   = (const float*)d_in[6];
  const float* bhh0   = (const float*)d_in[7];
  const float* Wih1   = (const float*)d_in[8];
  const float* Whh1   = (const float*)d_in[9];
  const float* bih1   = (const float*)d_in[10];
  const float* bhh1   = (const float*)d_in[11];
  const float* Wih2   = (const float*)d_in[12];
  const float* Whh2   = (const float*)d_in[13];
  const float* bih2   = (const float*)d_in[14];
  const float* bhh2   = (const float*)d_in[15];
  const float* fcW    = (const float*)d_in[16];
  const float* fcb    = (const float*)d_in[17];

  char* ws = (char*)d_ws;
  constexpr size_t OFF_X0   = 8192;                                  // counters at 0
  constexpr size_t OFF_XA   = OFF_X0   + (size_t)32768*192*2;
  constexpr size_t OFF_XB   = OFF_XA   + (size_t)32768*512*2;
  constexpr size_t OFF_X2F  = OFF_XB   + (size_t)32768*512*2;
  constexpr size_t OFF_HBF  = OFF_X2F  + (size_t)32768*512*4;
  constexpr size_t OFF_WHH  = OFF_HBF  + (size_t)2*131072*2;
  constexpr size_t OFF_WIH0 = OFF_WHH  + (size_t)3*1536*512*2;
  constexpr size_t OFF_WIH1 = OFF_WIH0 + (size_t)1536*192*2;
  constexpr size_t OFF_WIH2 = OFF_WIH1 + (size_t)1536*512*2;
  constexpr size_t OFF_FCWT = OFF_WIH2 + (size_t)1536*512*2;
  constexpr size_t OFF_GI   = OFF_FCWT + (size_t)512*64*4;

  int* cnt              = (int*)ws;
  unsigned short* x0    = (unsigned short*)(ws + OFF_X0);
  unsigned short* xa    = (unsigned short*)(ws + OFF_XA);
  unsigned short* xb    = (unsigned short*)(ws + OFF_XB);
  float* x2f            = (float*)(ws + OFF_X2F);
  unsigned short* hbf   = (unsigned short*)(ws + OFF_HBF);
  unsigned short* whb0  = (unsigned short*)(ws + OFF_WHH);
  unsigned short* whb1  = whb0 + (size_t)1536*512;
  unsigned short* whb2  = whb1 + (size_t)1536*512;
  unsigned short* wih0p = (unsigned short*)(ws + OFF_WIH0);
  unsigned short* wih1b = (unsigned short*)(ws + OFF_WIH1);
  unsigned short* wih2b = (unsigned short*)(ws + OFF_WIH2);
  float* fcwt           = (float*)(ws + OFF_FCWT);
  void* gi              = (void*)(ws + OFF_GI);
  int gi_bf16 = (ws_size >= OFF_GI + (size_t)32768*1536*4) ? 0 : 1;  // f32 gi if ws permits

  kconv5<<<3072, 256, 0, stream>>>(Whh0, Whh1, Whh2, Wih1, Wih2, whb0, whb1, whb2, wih1b, wih2b);
  kmisc <<<1152, 256, 0, stream>>>(Wih0, wih0p, fcW, fcwt, cnt);
  kx0   <<<8192, 192, 0, stream>>>(latent, enth, inp, emb, x0);

  kgemm<<<dim3(12,256), 256, 0, stream>>>(x0, wih0p, bih0, gi, gi_bf16, 1536, 192);
  kgru <<<64, 768, 0, stream>>>(whb0, bhh0, gi, gi_bf16, hbf, xa, x2f, cnt, 1, 0);
  kgemm<<<dim3(12,256), 256, 0, stream>>>(xa, wih1b, bih1, gi, gi_bf16, 1536, 512);
  kgru <<<64, 768, 0, stream>>>(whb1, bhh1, gi, gi_bf16, hbf, xb, x2f, cnt + 512, 1, 0);
  kgemm<<<dim3(12,256), 256, 0, stream>>>(xb, wih2b, bih2, gi, gi_bf16, 1536, 512);
  kgru <<<64, 768, 0, stream>>>(whb2, bhh2, gi, gi_bf16, hbf, xa, x2f, cnt + 1024, 0, 1);
  kfc  <<<2048, 256, 0, stream>>>(x2f, fcwt, fcb, (float*)d_out);
}

// Round 3
// 3084.462 us; speedup vs baseline: 1.4819x; 1.4819x over previous
//
#include <hip/hip_runtime.h>
#include <stdint.h>

// CondDecoder: B=256, T=128, V=64, L=128, H=512, E=32, NL=3, IN0=161 (pad 192)
#define BB 256
#define TT 128
#define HH 512
#define G3 1536

typedef __attribute__((ext_vector_type(8))) short bf16x8;
typedef __attribute__((ext_vector_type(4))) float f32x4;

__device__ __forceinline__ unsigned short f2bf(float f){
  unsigned int x = __builtin_bit_cast(unsigned int, f);
  x = x + 0x7fffu + ((x >> 16) & 1u);
  return (unsigned short)(x >> 16);
}
__device__ __forceinline__ float bf2f(unsigned short u){
  unsigned int x = ((unsigned int)u) << 16;
  return __builtin_bit_cast(float, x);
}
__device__ __forceinline__ void gl_lds16(const void* g, void* l){
  __builtin_amdgcn_global_load_lds((const __attribute__((address_space(1))) unsigned int*)g,
                                   (__attribute__((address_space(3))) unsigned int*)l, 16, 0, 0);
}

// ---- prep: convert five [1536][512] f32 weights to bf16 (Whh0..2, Wih1, Wih2)
__global__ __launch_bounds__(256) void kconv5(
    const float* __restrict__ a0, const float* __restrict__ a1, const float* __restrict__ a2,
    const float* __restrict__ a3, const float* __restrict__ a4,
    unsigned short* __restrict__ d0, unsigned short* __restrict__ d1, unsigned short* __restrict__ d2,
    unsigned short* __restrict__ d3, unsigned short* __restrict__ d4){
  int i = blockIdx.x*256 + threadIdx.x;   // grid 3072*256 = 786432 exactly
  d0[i] = f2bf(a0[i]); d1[i] = f2bf(a1[i]); d2[i] = f2bf(a2[i]);
  d3[i] = f2bf(a3[i]); d4[i] = f2bf(a4[i]);
}

// ---- prep: Wih0 pad 161->192 to bf16; fc_W transpose to [512][64] f32; zero counters
__global__ __launch_bounds__(256) void kmisc(const float* __restrict__ wih0,
    unsigned short* __restrict__ wih0p, const float* __restrict__ fcw,
    float* __restrict__ fcwt, int* __restrict__ cnt){
  int i = blockIdx.x*256 + threadIdx.x;  // grid 1152*256 = 294912
  if (i < 1536*192){
    int n = i / 192, k = i - n*192;
    wih0p[i] = (k < 161) ? f2bf(wih0[n*161 + k]) : (unsigned short)0;
  }
  if (i < 512*64){
    int k = i >> 6, v = i & 63;
    fcwt[i] = fcw[v*512 + k];
  }
  if (i < 2048) cnt[i] = 0;
}

// ---- prep: build x0 [32768][192] bf16 (latent | shifted-embed | enthalpy | zeros)
__global__ __launch_bounds__(192) void kx0(const float* __restrict__ latent,
    const float* __restrict__ enth, const int* __restrict__ inp,
    const float* __restrict__ emb, unsigned short* __restrict__ x0){
  int c = threadIdx.x;
  #pragma unroll
  for (int mr = 0; mr < 4; ++mr){
    int m = blockIdx.x*4 + mr;       // grid 8192 -> m < 32768
    int b = m >> 7, t = m & 127;
    float v;
    if (c < 128) v = latent[b*128 + c];
    else if (c < 160){
      int tok = (t == 0) ? 0 : inp[b*128 + t - 1];
      v = emb[tok*32 + (c - 128)];
    }
    else if (c == 160) v = enth[b];
    else v = 0.f;
    x0[(size_t)m*192 + c] = f2bf(v);
  }
}

// ---- bf16 MFMA GEMM: C[m][n] = A[m][K] @ Bt[n][K]^T + bias[n]; M=32768 fixed by grid
__global__ __launch_bounds__(256) void kgemm(const unsigned short* __restrict__ A,
    const unsigned short* __restrict__ Bt, const float* __restrict__ bias,
    void* __restrict__ C, int c_bf16, int N, int K){
  __shared__ __align__(16) unsigned short As[128*32];
  __shared__ __align__(16) unsigned short Bs[128*32];
  const int m0 = blockIdx.y*128, n0 = blockIdx.x*128;
  const int wv = threadIdx.x >> 6, lane = threadIdx.x & 63;
  const int woffM = (wv >> 1)*64, woffN = (wv & 1)*64;
  f32x4 acc[4][4] = {};
  for (int k0 = 0; k0 < K; k0 += 32){
    __syncthreads();
    #pragma unroll
    for (int i = 0; i < 4; ++i){
      int e = wv*4 + i;
      int ee = e & 7;
      int row = ee*16 + (lane >> 2);
      if (e < 8) gl_lds16(A  + (size_t)(m0+row)*K + k0 + (lane & 3)*8, (void*)&As[ee*512]);
      else       gl_lds16(Bt + (size_t)(n0+row)*K + k0 + (lane & 3)*8, (void*)&Bs[ee*512]);
    }
    __syncthreads();
    bf16x8 af[4], bf_[4];
    #pragma unroll
    for (int mt = 0; mt < 4; ++mt)
      af[mt] = *(const bf16x8*)&As[(woffM + mt*16 + (lane & 15))*32 + (lane >> 4)*8];
    #pragma unroll
    for (int nt = 0; nt < 4; ++nt)
      bf_[nt] = *(const bf16x8*)&Bs[(woffN + nt*16 + (lane & 15))*32 + (lane >> 4)*8];
    #pragma unroll
    for (int mt = 0; mt < 4; ++mt)
      #pragma unroll
      for (int nt = 0; nt < 4; ++nt)
        acc[mt][nt] = __builtin_amdgcn_mfma_f32_16x16x32_bf16(af[mt], bf_[nt], acc[mt][nt], 0, 0, 0);
  }
  const int col = lane & 15, lq = lane >> 4;
  #pragma unroll
  for (int nt = 0; nt < 4; ++nt){
    float bv = bias[n0 + woffN + nt*16 + col];
    #pragma unroll
    for (int mt = 0; mt < 4; ++mt)
      #pragma unroll
      for (int r = 0; r < 4; ++r){
        int grow = m0 + woffM + mt*16 + lq*4 + r;
        int gcol = n0 + woffN + nt*16 + col;
        float v = acc[mt][nt][r] + bv;
        size_t idx = (size_t)grow*N + gcol;
        if (c_bf16) ((unsigned short*)C)[idx] = f2bf(v);
        else        ((float*)C)[idx] = v;
      }
  }
}

// ---- persistent GRU layer kernel.
// 64 blocks x 768 threads (12 waves = 3 gates x 4 col-chunks); 8 blocks per rowgroup.
// MANUAL COHERENCE (no acquire/release fences -> no buffer_inv / buffer_wbl2):
//   h exchanged as 2B RELAXED agent atomic stores (sc1 write-through to coherence point),
//   inline-asm s_waitcnt vmcnt(0), then RELAXED flag store. Readers spin on RELAXED flag
//   loads (sc1, no inv) and stage h via 8B RELAXED atomic loads (sc1, bypass stale L1/L2)
//   into XOR-swizzled LDS via ds_write_b64. Double-buffered h kills the read/write race.
__global__ __launch_bounds__(768, 3) void kgru(const unsigned short* __restrict__ Wb,
    const float* __restrict__ bhh, const void* __restrict__ gi, int gi_bf16,
    unsigned short* __restrict__ hb, unsigned short* __restrict__ xo_bf,
    float* __restrict__ xo_f, int* __restrict__ cnt, int store_bf, int store_f){
  const int rg = blockIdx.x & 7, cg = blockIdx.x >> 3;
  const int b0 = rg*32;
  const int tid = threadIdx.x;
  const int wv = tid >> 6, lane = tid & 63;
  const int g = wv >> 2, cc = wv & 3;           // gate 0..2, col-chunk 0..3
  const int col = lane & 15, lq = lane >> 4;
  const int gcol = cg*64 + cc*16 + col;         // column within 512
  const int ccol = cc*16 + col;                 // column within block's 64
  __shared__ __align__(16) unsigned short hs[32*512];
  __shared__ float rz[2][32][68];               // padded stride 68: 2-way max (free)
  bf16x8 wf[16];
  {
    const unsigned short* wbase = Wb + ((size_t)(g*512 + gcol))*512 + lq*8;
    #pragma unroll
    for (int ks = 0; ks < 16; ++ks) wf[ks] = *(const bf16x8*)(wbase + ks*32);
  }
  const float bias = bhh[g*512 + gcol];
  float h_old[2][4];
  #pragma unroll
  for (int mt = 0; mt < 2; ++mt)
    #pragma unroll
    for (int r = 0; r < 4; ++r) h_old[mt][r] = 0.f;
  const float* gif = (const float*)gi;
  const unsigned short* gih = (const unsigned short*)gi;
  int* myc = cnt + rg*32;                       // 32 slots: 8 blocks x 4 writer waves

  #pragma unroll 1
  for (int t = 0; t < TT; ++t){
    // gi loads issued early; latency hides under spin+stage
    float gval[2][4];
    #pragma unroll
    for (int mt = 0; mt < 2; ++mt)
      #pragma unroll
      for (int r = 0; r < 4; ++r){
        size_t gidx = ((size_t)(b0 + mt*16 + lq*4 + r)*TT + t)*G3 + g*512 + gcol;
        gval[mt][r] = gi_bf16 ? bf2f(gih[gidx]) : gif[gidx];
      }
    if (t > 0){
      // all-wave spin on 32 relaxed flags (no fences)
      while (!__all(__hip_atomic_load(myc + (lane & 31), __ATOMIC_RELAXED,
                                      __HIP_MEMORY_SCOPE_AGENT) >= t))
        __builtin_amdgcn_s_sleep(1);
      __builtin_amdgcn_sched_barrier(0);
      // stage 32x512 bf16 (64KB) via 8B relaxed atomic loads -> swizzled ds_write_b64
      const unsigned long long* hr8 =
          (const unsigned long long*)(hb + (t & 1)*131072 + (size_t)b0*512);
      char* hsb = (char*)hs;
      unsigned long long vv[5];
      #pragma unroll
      for (int j = 0; j < 5; ++j)
        vv[j] = __hip_atomic_load(hr8 + tid + j*768, __ATOMIC_RELAXED,
                                  __HIP_MEMORY_SCOPE_AGENT);
      unsigned long long vx = 0;
      if (tid < 256)
        vx = __hip_atomic_load(hr8 + 3840 + tid, __ATOMIC_RELAXED,
                               __HIP_MEMORY_SCOPE_AGENT);
      #pragma unroll
      for (int j = 0; j < 5; ++j){
        int u = tid + j*768;
        int row = u >> 7, c4 = u & 127;
        *(unsigned long long*)(hsb + row*1024 + (((c4 >> 1) ^ (row & 7)) << 4)
                               + ((c4 & 1) << 3)) = vv[j];
      }
      if (tid < 256){
        int u = 3840 + tid;
        int row = u >> 7, c4 = u & 127;
        *(unsigned long long*)(hsb + row*1024 + (((c4 >> 1) ^ (row & 7)) << 4)
                               + ((c4 & 1) << 3)) = vx;
      }
    }
    __syncthreads();
    f32x4 acc[2] = {};
    if (t > 0){
      f32x4 acc2[2] = {};
      #pragma unroll
      for (int ks = 0; ks < 8; ++ks)
        #pragma unroll
        for (int mt = 0; mt < 2; ++mt){
          int row = mt*16 + col;
          bf16x8 a0 = *(const bf16x8*)&hs[row*512 + (((ks*4 + lq) ^ (row & 7)))*8];
          bf16x8 a1 = *(const bf16x8*)&hs[row*512 + ((((ks+8)*4 + lq) ^ (row & 7)))*8];
          acc[mt]  = __builtin_amdgcn_mfma_f32_16x16x32_bf16(a0, wf[ks],   acc[mt],  0, 0, 0);
          acc2[mt] = __builtin_amdgcn_mfma_f32_16x16x32_bf16(a1, wf[ks+8], acc2[mt], 0, 0, 0);
        }
      #pragma unroll
      for (int mt = 0; mt < 2; ++mt) acc[mt] += acc2[mt];
    }
    if (g < 2){
      #pragma unroll
      for (int mt = 0; mt < 2; ++mt)
        #pragma unroll
        for (int r = 0; r < 4; ++r){
          int row = mt*16 + lq*4 + r;
          float pre = gval[mt][r] + acc[mt][r] + bias;
          rz[g][row][ccol] = 1.f/(1.f + __expf(-pre));
        }
    }
    __syncthreads();
    if (g == 2){
      unsigned short* hw = hb + ((t + 1) & 1)*131072;
      unsigned short hv[2][4]; float hf[2][4];
      #pragma unroll
      for (int mt = 0; mt < 2; ++mt)
        #pragma unroll
        for (int r = 0; r < 4; ++r){
          int row = mt*16 + lq*4 + r;
          float rr = rz[0][row][ccol];
          float zz = rz[1][row][ccol];
          float nn = tanhf(gval[mt][r] + rr*(acc[mt][r] + bias));
          float hn = (1.f - zz)*nn + zz*h_old[mt][r];
          h_old[mt][r] = hn;
          hf[mt][r] = hn;
          hv[mt][r] = f2bf(hn);
          // 2B relaxed agent atomic store: sc1 write-through, coalesced per 16-lane row
          __hip_atomic_store(&hw[(size_t)(b0 + row)*512 + gcol], hv[mt][r],
                             __ATOMIC_RELAXED, __HIP_MEMORY_SCOPE_AGENT);
        }
      asm volatile("s_waitcnt vmcnt(0)" ::: "memory");   // h at coherence point
      if (lane == 0)
        __hip_atomic_store(myc + (cg*4 + cc), t + 1, __ATOMIC_RELAXED,
                           __HIP_MEMORY_SCOPE_AGENT);
      __builtin_amdgcn_sched_barrier(0);                 // xo strictly after flag
      if (store_bf){
        #pragma unroll
        for (int mt = 0; mt < 2; ++mt)
          #pragma unroll
          for (int r = 0; r < 4; ++r){
            int row = mt*16 + lq*4 + r;
            __builtin_nontemporal_store(hv[mt][r],
                &xo_bf[((size_t)(b0 + row)*TT + t)*512 + gcol]);
          }
      }
      if (store_f){
        #pragma unroll
        for (int mt = 0; mt < 2; ++mt)
          #pragma unroll
          for (int r = 0; r < 4; ++r){
            int row = mt*16 + lq*4 + r;
            __builtin_nontemporal_store(hf[mt][r],
                &xo_f[((size_t)(b0 + row)*TT + t)*512 + gcol]);
          }
      }
    }
  }
}

// ---- final FC in f32 (precision): logits[m][64] = x[m][512] @ fcwt + fc_b
__global__ __launch_bounds__(256) void kfc(const float* __restrict__ x,
    const float* __restrict__ wt, const float* __restrict__ fcb, float* __restrict__ out){
  __shared__ __align__(16) float xs[16*512];
  const int m0 = blockIdx.x*16;   // grid 2048
  for (int c = threadIdx.x; c < 2048; c += 256){
    int row = c >> 7, o = c & 127;
    *(float4*)&xs[row*512 + o*4] = *(const float4*)(x + (size_t)(m0+row)*512 + o*4);
  }
  __syncthreads();
  const int colv = threadIdx.x & 63, rq = threadIdx.x >> 6;
  float a0 = 0.f, a1 = 0.f, a2 = 0.f, a3 = 0.f;
  const float* x0p = xs + (rq*4 + 0)*512;
  const float* x1p = xs + (rq*4 + 1)*512;
  const float* x2p = xs + (rq*4 + 2)*512;
  const float* x3p = xs + (rq*4 + 3)*512;
  #pragma unroll 8
  for (int k = 0; k < 512; ++k){
    float w = wt[k*64 + colv];
    a0 += w * x0p[k]; a1 += w * x1p[k]; a2 += w * x2p[k]; a3 += w * x3p[k];
  }
  float bv = fcb[colv];
  out[(size_t)(m0 + rq*4 + 0)*64 + colv] = a0 + bv;
  out[(size_t)(m0 + rq*4 + 1)*64 + colv] = a1 + bv;
  out[(size_t)(m0 + rq*4 + 2)*64 + colv] = a2 + bv;
  out[(size_t)(m0 + rq*4 + 3)*64 + colv] = a3 + bv;
}

extern "C" void kernel_launch(void* const* d_in, const int* in_sizes, int n_in,
                              void* d_out, int out_size, void* d_ws, size_t ws_size,
                              hipStream_t stream){
  const float* latent = (const float*)d_in[0];
  const float* enth   = (const float*)d_in[1];
  const int*   inp    = (const int*)d_in[2];
  const float* emb    = (const float*)d_in[3];
  const float* Wih0   = (const float*)d_in[4];
  const float* Whh0   = (const float*)d_in[5];
  const float* bih0   = (const float*)d_in[6];
  const float* bhh0   = (const float*)d_in[7];
  const float* Wih1   = (const float*)d_in[8];
  const float* Whh1   = (const float*)d_in[9];
  const float* bih1   = (const float*)d_in[10];
  const float* bhh1   = (const float*)d_in[11];
  const float* Wih2   = (const float*)d_in[12];
  const float* Whh2   = (const float*)d_in[13];
  const float* bih2   = (const float*)d_in[14];
  const float* bhh2   = (const float*)d_in[15];
  const float* fcW    = (const float*)d_in[16];
  const float* fcb    = (const float*)d_in[17];

  char* ws = (char*)d_ws;
  constexpr size_t OFF_X0   = 8192;                                  // counters at 0
  constexpr size_t OFF_XA   = OFF_X0   + (size_t)32768*192*2;
  constexpr size_t OFF_XB   = OFF_XA   + (size_t)32768*512*2;
  constexpr size_t OFF_X2F  = OFF_XB   + (size_t)32768*512*2;
  constexpr size_t OFF_HBF  = OFF_X2F  + (size_t)32768*512*4;
  constexpr size_t OFF_WHH  = OFF_HBF  + (size_t)2*131072*2;
  constexpr size_t OFF_WIH0 = OFF_WHH  + (size_t)3*1536*512*2;
  constexpr size_t OFF_WIH1 = OFF_WIH0 + (size_t)1536*192*2;
  constexpr size_t OFF_WIH2 = OFF_WIH1 + (size_t)1536*512*2;
  constexpr size_t OFF_FCWT = OFF_WIH2 + (size_t)1536*512*2;
  constexpr size_t OFF_GI   = OFF_FCWT + (size_t)512*64*4;

  int* cnt              = (int*)ws;
  unsigned short* x0    = (unsigned short*)(ws + OFF_X0);
  unsigned short* xa    = (unsigned short*)(ws + OFF_XA);
  unsigned short* xb    = (unsigned short*)(ws + OFF_XB);
  float* x2f            = (float*)(ws + OFF_X2F);
  unsigned short* hbf   = (unsigned short*)(ws + OFF_HBF);
  unsigned short* whb0  = (unsigned short*)(ws + OFF_WHH);
  unsigned short* whb1  = whb0 + (size_t)1536*512;
  unsigned short* whb2  = whb1 + (size_t)1536*512;
  unsigned short* wih0p = (unsigned short*)(ws + OFF_WIH0);
  unsigned short* wih1b = (unsigned short*)(ws + OFF_WIH1);
  unsigned short* wih2b = (unsigned short*)(ws + OFF_WIH2);
  float* fcwt           = (float*)(ws + OFF_FCWT);
  void* gi              = (void*)(ws + OFF_GI);
  int gi_bf16 = (ws_size >= OFF_GI + (size_t)32768*1536*4) ? 0 : 1;  // f32 gi if ws permits

  kconv5<<<3072, 256, 0, stream>>>(Whh0, Whh1, Whh2, Wih1, Wih2, whb0, whb1, whb2, wih1b, wih2b);
  kmisc <<<1152, 256, 0, stream>>>(Wih0, wih0p, fcW, fcwt, cnt);
  kx0   <<<8192, 192, 0, stream>>>(latent, enth, inp, emb, x0);

  kgemm<<<dim3(12,256), 256, 0, stream>>>(x0, wih0p, bih0, gi, gi_bf16, 1536, 192);
  kgru <<<64, 768, 0, stream>>>(whb0, bhh0, gi, gi_bf16, hbf, xa, x2f, cnt, 1, 0);
  kgemm<<<dim3(12,256), 256, 0, stream>>>(xa, wih1b, bih1, gi, gi_bf16, 1536, 512);
  kgru <<<64, 768, 0, stream>>>(whb1, bhh1, gi, gi_bf16, hbf, xb, x2f, cnt + 512, 1, 0);
  kgemm<<<dim3(12,256), 256, 0, stream>>>(xb, wih2b, bih2, gi, gi_bf16, 1536, 512);
  kgru <<<64, 768, 0, stream>>>(whb2, bhh2, gi, gi_bf16, hbf, xa, x2f, cnt + 1024, 0, 1);
  kfc  <<<2048, 256, 0, stream>>>(x2f, fcwt, fcb, (float*)d_out);
}